// Round 8
// baseline (169.904 us; speedup 1.0000x reference)
//
#include <hip/hip_runtime.h>

#define IN_DIM     128
#define OUT_DIM    64
#define BSHIFT     6                  // 64 nodes per bucket
#define BSZ        64
#define NBUCK_MAX  2048               // covers N <= 131072
#define EPB        4096               // edges per block in hist/bucket passes

// bf16 helpers (manual RNE pack, bit-shift unpack)
__device__ __forceinline__ unsigned int f2bf_rne(float f) {
    unsigned int b = __float_as_uint(f);
    return (b + 0x7FFFu + ((b >> 16) & 1u)) >> 16;
}
__device__ __forceinline__ float bf_lo(unsigned int v) { return __uint_as_float(v << 16); }
__device__ __forceinline__ float bf_hi(unsigned int v) { return __uint_as_float(v & 0xFFFF0000u); }

// ---------------------------------------------------------------------------
// Zero ints (grid-stride)
// ---------------------------------------------------------------------------
__global__ void zero_i_kernel(int* __restrict__ p, int n) {
    int i = blockIdx.x * blockDim.x + threadIdx.x;
    int s = gridDim.x * blockDim.x;
    for (; i < n; i += s) p[i] = 0;
}

// ---------------------------------------------------------------------------
// Bucket-level histogram (LDS-aggregated; no per-node atomics)
// ---------------------------------------------------------------------------
__global__ __launch_bounds__(256) void hist_kernel(
        const int* __restrict__ col, int* __restrict__ bhist, int E, int nbuck) {
    __shared__ int h[NBUCK_MAX];
    for (int i = threadIdx.x; i < nbuck; i += 256) h[i] = 0;
    __syncthreads();

    const int base = blockIdx.x * EPB;
    const int end  = min(base + EPB, E);
    for (int e = base + threadIdx.x; e < end; e += 256)
        atomicAdd(&h[col[e] >> BSHIFT], 1);
    __syncthreads();

    for (int i = threadIdx.x; i < nbuck; i += 256) {
        int v = h[i];
        if (v) atomicAdd(&bhist[i], v);
    }
}

// ---------------------------------------------------------------------------
// Exclusive scan of bhist -> bstart[0..nbuck]  (single block, 8 elems/thread)
// ---------------------------------------------------------------------------
__global__ __launch_bounds__(256) void scanb_kernel(
        const int* __restrict__ bhist, int* __restrict__ bstart, int nbuck) {
    __shared__ int ssum[256];
    const int t = threadIdx.x;
    int v[8];
    int run = 0;
#pragma unroll
    for (int j = 0; j < 8; ++j) {
        int idx = t * 8 + j;
        int x = (idx < nbuck) ? bhist[idx] : 0;
        v[j] = run;
        run += x;
    }
    ssum[t] = run;
    __syncthreads();
    for (int off = 1; off < 256; off <<= 1) {
        int tmp = (t >= off) ? ssum[t - off] : 0;
        __syncthreads();
        ssum[t] += tmp;
        __syncthreads();
    }
    int offset = (t > 0) ? ssum[t - 1] : 0;
#pragma unroll
    for (int j = 0; j < 8; ++j) {
        int idx = t * 8 + j;
        if (idx < nbuck) bstart[idx] = offset + v[j];
    }
    if (t == 255) bstart[nbuck] = ssum[255];   // total = E
}

// ---------------------------------------------------------------------------
// Scatter edges into bucket-major tmp, packed (r<<6 | c&63).
// Block-aggregated reserve -> per-bucket ~sequential write runs.
// ---------------------------------------------------------------------------
__global__ __launch_bounds__(256) void bucket_kernel(
        const int* __restrict__ eidx, const int* __restrict__ bstart,
        int* __restrict__ bcursor, int* __restrict__ tmp, int E, int nbuck) {
    __shared__ int hcnt[NBUCK_MAX];
    __shared__ int hbase[NBUCK_MAX];
    for (int i = threadIdx.x; i < nbuck; i += 256) hcnt[i] = 0;
    __syncthreads();

    const int base = blockIdx.x * EPB;
    const int end  = min(base + EPB, E);

    for (int e = base + threadIdx.x; e < end; e += 256)
        atomicAdd(&hcnt[eidx[E + e] >> BSHIFT], 1);
    __syncthreads();

    for (int i = threadIdx.x; i < nbuck; i += 256) {
        int n = hcnt[i];
        hbase[i] = n ? (bstart[i] + atomicAdd(&bcursor[i], n)) : 0;
        hcnt[i] = 0;           // reuse as local cursor
    }
    __syncthreads();

    for (int e = base + threadIdx.x; e < end; e += 256) {
        int r = eidx[e];
        int c = eidx[E + e];
        int bb = c >> BSHIFT;
        int ofs = atomicAdd(&hcnt[bb], 1);
        tmp[hbase[bb] + ofs] = (r << BSHIFT) | (c & (BSZ - 1));
    }
}

// ---------------------------------------------------------------------------
// Per-bucket: count 64 node degrees in LDS -> rowptr + dis (byproducts),
// then exact CSR placement. All traffic is the bucket's own ~4KB region.
// ---------------------------------------------------------------------------
__global__ __launch_bounds__(256) void sortloc_kernel(
        const int* __restrict__ tmp, const int* __restrict__ bstart,
        int* __restrict__ src, int* __restrict__ rowptr, float* __restrict__ dis,
        int N) {
    __shared__ int cnt[BSZ];
    __shared__ int pref[BSZ];
    __shared__ int scur[BSZ];

    const int bucket = blockIdx.x;
    const int sbeg = bstart[bucket];
    const int send = bstart[bucket + 1];
    const int tid = threadIdx.x;

    if (tid < BSZ) { cnt[tid] = 0; scur[tid] = 0; }
    __syncthreads();

    for (int i = sbeg + tid; i < send; i += 256)
        atomicAdd(&cnt[tmp[i] & (BSZ - 1)], 1);
    __syncthreads();

    if (tid == 0) {
        int run = 0;
#pragma unroll
        for (int j = 0; j < BSZ; ++j) { pref[j] = run; run += cnt[j]; }
    }
    __syncthreads();

    if (tid < BSZ) {
        int node = (bucket << BSHIFT) + tid;
        if (node < N) {
            rowptr[node] = sbeg + pref[tid];
            float d = (float)cnt[tid];
            dis[node] = (d > 0.f) ? rsqrtf(d) : 0.f;
        }
    }
    __syncthreads();

    for (int i = sbeg + tid; i < send; i += 256) {
        int p = tmp[i];
        int c = p & (BSZ - 1);
        int pos = sbeg + pref[c] + atomicAdd(&scur[c], 1);
        src[pos] = p >> BSHIFT;
    }
}

// ---------------------------------------------------------------------------
// hsb = bf16( (x @ W) * dis[row] )  packed 2 cols/uint: N rows x 32 uints
// ---------------------------------------------------------------------------
__global__ __launch_bounds__(256) void linear_kernel(
        const float* __restrict__ x, const float* __restrict__ W,
        const float* __restrict__ dis, unsigned int* __restrict__ hsb, int nrows) {
    __shared__ float sW[IN_DIM * OUT_DIM];   // 32 KB
    __shared__ float sx[4][IN_DIM];

    const int tid = threadIdx.x;
    for (int i = tid; i < IN_DIM * OUT_DIM; i += 256) sW[i] = W[i];
    __syncthreads();

    const int wave = tid >> 6;
    const int lane = tid & 63;

    for (int r = blockIdx.x * 4 + wave; r < nrows; r += gridDim.x * 4) {
        sx[wave][lane]      = x[(size_t)r * IN_DIM + lane];
        sx[wave][lane + 64] = x[(size_t)r * IN_DIM + 64 + lane];

        float acc = 0.f;
#pragma unroll
        for (int k = 0; k < IN_DIM; k += 4) {
            float4 xv = *reinterpret_cast<const float4*>(&sx[wave][k]);
            acc = fmaf(xv.x, sW[(k + 0) * OUT_DIM + lane], acc);
            acc = fmaf(xv.y, sW[(k + 1) * OUT_DIM + lane], acc);
            acc = fmaf(xv.z, sW[(k + 2) * OUT_DIM + lane], acc);
            acc = fmaf(xv.w, sW[(k + 3) * OUT_DIM + lane], acc);
        }
        float accf = acc * dis[r];
        float nxt = __shfl_down(accf, 1, 64);
        if ((lane & 1) == 0) {
            unsigned int pk = f2bf_rne(accf) | (f2bf_rne(nxt) << 16);
            hsb[(size_t)r * (OUT_DIM / 2) + (lane >> 1)] = pk;
        }
    }
}

// ---------------------------------------------------------------------------
// Aggregate + bias + PReLU: one wave per target node; each 32-lane half
// processes its own edge (32 lanes x bf16x2 = 128B row), halves combined
// at the end via shfl_xor(32).
// ---------------------------------------------------------------------------
__global__ __launch_bounds__(256) void agg_kernel(
        const int* __restrict__ rowptr, const int* __restrict__ src,
        const unsigned int* __restrict__ hsb, const float* __restrict__ dis,
        const float* __restrict__ b, const float* __restrict__ prelu_a,
        float* __restrict__ out, int N, int E) {
    const int lane = threadIdx.x & 63;
    const int half = lane >> 5;
    const int l32  = lane & 31;
    const int node = (blockIdx.x * blockDim.x + threadIdx.x) >> 6;
    if (node >= N) return;

    const int beg = rowptr[node];
    const int end = (node + 1 < N) ? rowptr[node + 1] : E;

    float a0 = 0.f, a1 = 0.f;
    int p = beg + half;
    // 4 independent gathers in flight per half-wave
    for (; p + 6 < end; p += 8) {
        int r0 = src[p], r1 = src[p + 2], r2 = src[p + 4], r3 = src[p + 6];
        unsigned int v0 = hsb[(size_t)r0 * (OUT_DIM / 2) + l32];
        unsigned int v1 = hsb[(size_t)r1 * (OUT_DIM / 2) + l32];
        unsigned int v2 = hsb[(size_t)r2 * (OUT_DIM / 2) + l32];
        unsigned int v3 = hsb[(size_t)r3 * (OUT_DIM / 2) + l32];
        a0 += bf_lo(v0) + bf_lo(v1) + bf_lo(v2) + bf_lo(v3);
        a1 += bf_hi(v0) + bf_hi(v1) + bf_hi(v2) + bf_hi(v3);
    }
    for (; p < end; p += 2) {
        unsigned int v = hsb[(size_t)src[p] * (OUT_DIM / 2) + l32];
        a0 += bf_lo(v);
        a1 += bf_hi(v);
    }

    // combine the two halves
    a0 += __shfl_xor(a0, 32, 64);
    a1 += __shfl_xor(a1, 32, 64);

    if (half == 0) {
        const float dn = dis[node];
        const float pa = prelu_a[0];
        int c0 = l32 * 2;
        float o0 = a0 * dn + b[c0];
        float o1 = a1 * dn + b[c0 + 1];
        o0 = (o0 >= 0.f) ? o0 : pa * o0;
        o1 = (o1 >= 0.f) ? o1 : pa * o1;
        *reinterpret_cast<float2*>(&out[(size_t)node * OUT_DIM + c0]) = make_float2(o0, o1);
    }
}

extern "C" void kernel_launch(void* const* d_in, const int* in_sizes, int n_in,
                              void* d_out, int out_size, void* d_ws, size_t ws_size,
                              hipStream_t stream) {
    const float* x    = (const float*)d_in[0];
    const int*   eidx = (const int*)d_in[1];
    const float* W    = (const float*)d_in[2];
    const float* b    = (const float*)d_in[3];
    const float* pa   = (const float*)d_in[4];
    float* out = (float*)d_out;

    const int N = in_sizes[0] / IN_DIM;        // 100000
    const int E = in_sizes[1] / 2;             // 1600000
    const int nbuck = (N + BSZ - 1) >> BSHIFT; // 1563
    const int nchunk = (E + EPB - 1) / EPB;    // 391

    // workspace layout (4-byte elements):
    unsigned int* hsb = (unsigned int*)d_ws;             // N*32 (bf16x2)
    int*   bhist   = (int*)(hsb + (size_t)N * (OUT_DIM / 2)); // NBUCK_MAX
    int*   bcursor = bhist + NBUCK_MAX;                  // NBUCK_MAX
    int*   bstart  = bcursor + NBUCK_MAX;                // NBUCK_MAX+1
    int*   rowptr  = bstart + NBUCK_MAX + 1;             // N
    float* dis     = (float*)(rowptr + N);               // N
    int*   tmp     = (int*)(dis + N);                    // E
    int*   src     = tmp + E;                            // E

    // 1) zero bhist + bcursor (contiguous, tiny)
    zero_i_kernel<<<16, 256, 0, stream>>>(bhist, 2 * NBUCK_MAX);

    // 2) bucket histogram
    hist_kernel<<<nchunk, 256, 0, stream>>>(eidx + E, bhist, E, nbuck);

    // 3) scan bhist -> bstart (+ total)
    scanb_kernel<<<1, 256, 0, stream>>>(bhist, bstart, nbuck);

    // 4) bucket-major scatter
    bucket_kernel<<<nchunk, 256, 0, stream>>>(eidx, bstart, bcursor, tmp, E, nbuck);

    // 5) per-bucket placement; emits rowptr + dis
    sortloc_kernel<<<nbuck, 256, 0, stream>>>(tmp, bstart, src, rowptr, dis, N);

    // 6) hsb = bf16((x @ W) * dis[row])
    linear_kernel<<<2048, 256, 0, stream>>>(x, W, dis, hsb, N);

    // 7) aggregate + bias + PReLU
    agg_kernel<<<(N * 64 + 255) / 256, 256, 0, stream>>>(
        rowptr, src, hsb, dis, b, pa, out, N, E);
}

// Round 9
// 133.212 us; speedup vs baseline: 1.2754x; 1.2754x over previous
//
#include <hip/hip_runtime.h>
#include <hip/hip_bf16.h>

#define IN_DIM     128
#define OUT_DIM    64
#define BSHIFT     6                  // 64 nodes per bucket
#define BSZ        64
#define NBUCK_MAX  2048               // covers N <= 131072
#define EPB        4096               // edges per block in hist/bucket passes

typedef __attribute__((ext_vector_type(4))) float  f32x4;
typedef __attribute__((ext_vector_type(8))) short  bf16x8;

// bf16 helpers
__device__ __forceinline__ unsigned int pk_bf2(float lo, float hi) {
    __hip_bfloat162 h = __float22bfloat162_rn(make_float2(lo, hi));
    unsigned int u;
    __builtin_memcpy(&u, &h, 4);
    return u;
}
__device__ __forceinline__ float bf_lo(unsigned int v) { return __uint_as_float(v << 16); }
__device__ __forceinline__ float bf_hi(unsigned int v) { return __uint_as_float(v & 0xFFFF0000u); }

// ---------------------------------------------------------------------------
// Zero ints (grid-stride)
// ---------------------------------------------------------------------------
__global__ void zero_i_kernel(int* __restrict__ p, int n) {
    int i = blockIdx.x * blockDim.x + threadIdx.x;
    int s = gridDim.x * blockDim.x;
    for (; i < n; i += s) p[i] = 0;
}

// ---------------------------------------------------------------------------
// Bucket-level histogram (LDS-aggregated; no per-node atomics)
// ---------------------------------------------------------------------------
__global__ __launch_bounds__(256) void hist_kernel(
        const int* __restrict__ col, int* __restrict__ bhist, int E, int nbuck) {
    __shared__ int h[NBUCK_MAX];
    for (int i = threadIdx.x; i < nbuck; i += 256) h[i] = 0;
    __syncthreads();

    const int base = blockIdx.x * EPB;
    const int end  = min(base + EPB, E);
    for (int e = base + threadIdx.x; e < end; e += 256)
        atomicAdd(&h[col[e] >> BSHIFT], 1);
    __syncthreads();

    for (int i = threadIdx.x; i < nbuck; i += 256) {
        int v = h[i];
        if (v) atomicAdd(&bhist[i], v);
    }
}

// ---------------------------------------------------------------------------
// Exclusive scan of bhist -> bstart[0..nbuck]  (single block, 8 elems/thread)
// ---------------------------------------------------------------------------
__global__ __launch_bounds__(256) void scanb_kernel(
        const int* __restrict__ bhist, int* __restrict__ bstart, int nbuck) {
    __shared__ int ssum[256];
    const int t = threadIdx.x;
    int v[8];
    int run = 0;
#pragma unroll
    for (int j = 0; j < 8; ++j) {
        int idx = t * 8 + j;
        int x = (idx < nbuck) ? bhist[idx] : 0;
        v[j] = run;
        run += x;
    }
    ssum[t] = run;
    __syncthreads();
    for (int off = 1; off < 256; off <<= 1) {
        int tmp = (t >= off) ? ssum[t - off] : 0;
        __syncthreads();
        ssum[t] += tmp;
        __syncthreads();
    }
    int offset = (t > 0) ? ssum[t - 1] : 0;
#pragma unroll
    for (int j = 0; j < 8; ++j) {
        int idx = t * 8 + j;
        if (idx < nbuck) bstart[idx] = offset + v[j];
    }
    if (t == 255) bstart[nbuck] = ssum[255];   // total = E
}

// ---------------------------------------------------------------------------
// Scatter edges into bucket-major tmp, packed (r<<6 | c&63).
// ---------------------------------------------------------------------------
__global__ __launch_bounds__(256) void bucket_kernel(
        const int* __restrict__ eidx, const int* __restrict__ bstart,
        int* __restrict__ bcursor, int* __restrict__ tmp, int E, int nbuck) {
    __shared__ int hcnt[NBUCK_MAX];
    __shared__ int hbase[NBUCK_MAX];
    for (int i = threadIdx.x; i < nbuck; i += 256) hcnt[i] = 0;
    __syncthreads();

    const int base = blockIdx.x * EPB;
    const int end  = min(base + EPB, E);

    for (int e = base + threadIdx.x; e < end; e += 256)
        atomicAdd(&hcnt[eidx[E + e] >> BSHIFT], 1);
    __syncthreads();

    for (int i = threadIdx.x; i < nbuck; i += 256) {
        int n = hcnt[i];
        hbase[i] = n ? (bstart[i] + atomicAdd(&bcursor[i], n)) : 0;
        hcnt[i] = 0;           // reuse as local cursor
    }
    __syncthreads();

    for (int e = base + threadIdx.x; e < end; e += 256) {
        int r = eidx[e];
        int c = eidx[E + e];
        int bb = c >> BSHIFT;
        int ofs = atomicAdd(&hcnt[bb], 1);
        tmp[hbase[bb] + ofs] = (r << BSHIFT) | (c & (BSZ - 1));
    }
}

// ---------------------------------------------------------------------------
// Per-bucket: degree count -> rowptr + dis, then exact CSR placement.
// ---------------------------------------------------------------------------
__global__ __launch_bounds__(256) void sortloc_kernel(
        const int* __restrict__ tmp, const int* __restrict__ bstart,
        int* __restrict__ src, int* __restrict__ rowptr, float* __restrict__ dis,
        int N) {
    __shared__ int cnt[BSZ];
    __shared__ int pref[BSZ];
    __shared__ int scur[BSZ];

    const int bucket = blockIdx.x;
    const int sbeg = bstart[bucket];
    const int send = bstart[bucket + 1];
    const int tid = threadIdx.x;

    if (tid < BSZ) { cnt[tid] = 0; scur[tid] = 0; }
    __syncthreads();

    for (int i = sbeg + tid; i < send; i += 256)
        atomicAdd(&cnt[tmp[i] & (BSZ - 1)], 1);
    __syncthreads();

    if (tid == 0) {
        int run = 0;
#pragma unroll
        for (int j = 0; j < BSZ; ++j) { pref[j] = run; run += cnt[j]; }
    }
    __syncthreads();

    if (tid < BSZ) {
        int node = (bucket << BSHIFT) + tid;
        if (node < N) {
            rowptr[node] = sbeg + pref[tid];
            float d = (float)cnt[tid];
            dis[node] = (d > 0.f) ? rsqrtf(d) : 0.f;
        }
    }
    __syncthreads();

    for (int i = sbeg + tid; i < send; i += 256) {
        int p = tmp[i];
        int c = p & (BSZ - 1);
        int pos = sbeg + pref[c] + atomicAdd(&scur[c], 1);
        src[pos] = p >> BSHIFT;
    }
}

// ---------------------------------------------------------------------------
// MFMA linear: hsb = bf16( (x @ W) * dis[row] ), packed 2 cols/uint.
// W staged per-block in LDS in fragment order (bf16); B frags live in VGPRs.
// One 16-row tile per wave; 16 x mfma_f32_16x16x32_bf16 per tile.
// Layouts (m89-verified): A row=lane&15, k=(lane>>4)*8+j; B col=lane&15,
// same k; D col=lane&15, row=(lane>>4)*4+reg.
// ---------------------------------------------------------------------------
__global__ __launch_bounds__(256) void linear_mfma_kernel(
        const float* __restrict__ x, const float* __restrict__ W,
        const float* __restrict__ dis, unsigned int* __restrict__ hsb, int nrows) {
    __shared__ unsigned int sB[16 * 64 * 4];   // 16 KB: [frag][lane][4 uints]

    const int tid   = threadIdx.x;
    const int lane6 = tid & 63;
    const int wv    = tid >> 6;

    // cooperative W -> bf16 frag staging (each wave fills frags wv,wv+4,wv+8,wv+12)
#pragma unroll
    for (int ii = 0; ii < 4; ++ii) {
        int f  = ii * 4 + wv;
        int ct = f >> 2, kt = f & 3;
        int n  = ct * 16 + (lane6 & 15);
        int kb = kt * 32 + (lane6 >> 4) * 8;
        unsigned int q[4];
#pragma unroll
        for (int e = 0; e < 4; ++e)
            q[e] = pk_bf2(W[(kb + 2 * e) * OUT_DIM + n],
                          W[(kb + 2 * e + 1) * OUT_DIM + n]);
        *reinterpret_cast<uint4*>(&sB[(f * 64 + lane6) * 4]) =
            *reinterpret_cast<uint4*>(q);
    }
    __syncthreads();

    const int tile    = blockIdx.x * 4 + wv;
    const int rowbase = tile * 16;
    if (rowbase >= nrows) return;

    // B frags: LDS -> VGPR (held for the whole tile)
    bf16x8 b[16];
#pragma unroll
    for (int f = 0; f < 16; ++f)
        b[f] = *reinterpret_cast<const bf16x8*>(&sB[(f * 64 + lane6) * 4]);

    // A frags: global -> cvt bf16
    const int arow  = rowbase + (lane6 & 15);
    const int kbase = (lane6 >> 4) * 8;
    bf16x8 a[4];
#pragma unroll
    for (int kt = 0; kt < 4; ++kt) {
        const float4* p = reinterpret_cast<const float4*>(
            &x[(size_t)arow * IN_DIM + kt * 32 + kbase]);
        float4 f0 = p[0], f1 = p[1];
        unsigned int q[4] = { pk_bf2(f0.x, f0.y), pk_bf2(f0.z, f0.w),
                              pk_bf2(f1.x, f1.y), pk_bf2(f1.z, f1.w) };
        a[kt] = *reinterpret_cast<bf16x8*>(q);
    }

    f32x4 acc[4] = {{0,0,0,0},{0,0,0,0},{0,0,0,0},{0,0,0,0}};
#pragma unroll
    for (int ct = 0; ct < 4; ++ct)
#pragma unroll
        for (int kt = 0; kt < 4; ++kt)
            acc[ct] = __builtin_amdgcn_mfma_f32_16x16x32_bf16(
                a[kt], b[ct * 4 + kt], acc[ct], 0, 0, 0);

    // epilogue: * dis[row], pack col pairs, store
    const int rbase = rowbase + (lane6 >> 4) * 4;
    float dn[4];
#pragma unroll
    for (int r = 0; r < 4; ++r) dn[r] = dis[rbase + r];

#pragma unroll
    for (int ct = 0; ct < 4; ++ct) {
#pragma unroll
        for (int r = 0; r < 4; ++r) {
            float v = acc[ct][r] * dn[r];
            float vn = __shfl_down(v, 1, 64);
            if ((lane6 & 1) == 0) {
                int cpair = ct * 8 + ((lane6 & 15) >> 1);
                hsb[(size_t)(rbase + r) * (OUT_DIM / 2) + cpair] = pk_bf2(v, vn);
            }
        }
    }
}

// ---------------------------------------------------------------------------
// Aggregate + bias + PReLU: one wave per target node; each 32-lane half
// processes its own edge (32 lanes x bf16x2 = 128B row); halves combined
// via shfl_xor(32).
// ---------------------------------------------------------------------------
__global__ __launch_bounds__(256) void agg_kernel(
        const int* __restrict__ rowptr, const int* __restrict__ src,
        const unsigned int* __restrict__ hsb, const float* __restrict__ dis,
        const float* __restrict__ b, const float* __restrict__ prelu_a,
        float* __restrict__ out, int N, int E) {
    const int lane = threadIdx.x & 63;
    const int half = lane >> 5;
    const int l32  = lane & 31;
    const int node = (blockIdx.x * blockDim.x + threadIdx.x) >> 6;
    if (node >= N) return;

    const int beg = rowptr[node];
    const int end = (node + 1 < N) ? rowptr[node + 1] : E;

    float a0 = 0.f, a1 = 0.f;
    int p = beg + half;
    for (; p + 6 < end; p += 8) {
        int r0 = src[p], r1 = src[p + 2], r2 = src[p + 4], r3 = src[p + 6];
        unsigned int v0 = hsb[(size_t)r0 * (OUT_DIM / 2) + l32];
        unsigned int v1 = hsb[(size_t)r1 * (OUT_DIM / 2) + l32];
        unsigned int v2 = hsb[(size_t)r2 * (OUT_DIM / 2) + l32];
        unsigned int v3 = hsb[(size_t)r3 * (OUT_DIM / 2) + l32];
        a0 += bf_lo(v0) + bf_lo(v1) + bf_lo(v2) + bf_lo(v3);
        a1 += bf_hi(v0) + bf_hi(v1) + bf_hi(v2) + bf_hi(v3);
    }
    for (; p < end; p += 2) {
        unsigned int v = hsb[(size_t)src[p] * (OUT_DIM / 2) + l32];
        a0 += bf_lo(v);
        a1 += bf_hi(v);
    }

    a0 += __shfl_xor(a0, 32, 64);
    a1 += __shfl_xor(a1, 32, 64);

    if (half == 0) {
        const float dn = dis[node];
        const float pa = prelu_a[0];
        int c0 = l32 * 2;
        float o0 = a0 * dn + b[c0];
        float o1 = a1 * dn + b[c0 + 1];
        o0 = (o0 >= 0.f) ? o0 : pa * o0;
        o1 = (o1 >= 0.f) ? o1 : pa * o1;
        *reinterpret_cast<float2*>(&out[(size_t)node * OUT_DIM + c0]) = make_float2(o0, o1);
    }
}

extern "C" void kernel_launch(void* const* d_in, const int* in_sizes, int n_in,
                              void* d_out, int out_size, void* d_ws, size_t ws_size,
                              hipStream_t stream) {
    const float* x    = (const float*)d_in[0];
    const int*   eidx = (const int*)d_in[1];
    const float* W    = (const float*)d_in[2];
    const float* b    = (const float*)d_in[3];
    const float* pa   = (const float*)d_in[4];
    float* out = (float*)d_out;

    const int N = in_sizes[0] / IN_DIM;        // 100000
    const int E = in_sizes[1] / 2;             // 1600000
    const int nbuck = (N + BSZ - 1) >> BSHIFT; // 1563
    const int nchunk = (E + EPB - 1) / EPB;    // 391
    const int ntiles = (N + 15) / 16;          // 6250
    const int nblk_lin = (ntiles + 3) / 4;     // 1563

    // workspace layout (4-byte elements):
    unsigned int* hsb = (unsigned int*)d_ws;                  // N*32 (bf16x2)
    int*   bhist   = (int*)(hsb + (size_t)N * (OUT_DIM / 2)); // NBUCK_MAX
    int*   bcursor = bhist + NBUCK_MAX;                       // NBUCK_MAX
    int*   bstart  = bcursor + NBUCK_MAX;                     // NBUCK_MAX+1
    int*   rowptr  = bstart + NBUCK_MAX + 1;                  // N
    float* dis     = (float*)(rowptr + N);                    // N
    int*   tmp     = (int*)(dis + N);                         // E
    int*   src     = tmp + E;                                 // E

    // 1) zero bhist + bcursor
    zero_i_kernel<<<16, 256, 0, stream>>>(bhist, 2 * NBUCK_MAX);

    // 2) bucket histogram
    hist_kernel<<<nchunk, 256, 0, stream>>>(eidx + E, bhist, E, nbuck);

    // 3) scan bhist -> bstart (+ total)
    scanb_kernel<<<1, 256, 0, stream>>>(bhist, bstart, nbuck);

    // 4) bucket-major scatter
    bucket_kernel<<<nchunk, 256, 0, stream>>>(eidx, bstart, bcursor, tmp, E, nbuck);

    // 5) per-bucket placement; emits rowptr + dis
    sortloc_kernel<<<nbuck, 256, 0, stream>>>(tmp, bstart, src, rowptr, dis, N);

    // 6) hsb = bf16((x @ W) * dis[row])  [MFMA]
    linear_mfma_kernel<<<nblk_lin, 256, 0, stream>>>(x, W, dis, hsb, N);

    // 7) aggregate + bias + PReLU
    agg_kernel<<<(N * 64 + 255) / 256, 256, 0, stream>>>(
        rowptr, src, hsb, dis, b, pa, out, N, E);
}

// Round 10
// 132.973 us; speedup vs baseline: 1.2777x; 1.0018x over previous
//
#include <hip/hip_runtime.h>
#include <hip/hip_bf16.h>

#define IN_DIM     128
#define OUT_DIM    64
#define BSHIFT     6                  // 64 nodes per bucket
#define BSZ        64
#define NBUCK_MAX  2048               // covers N <= 131072
#define EPB        4096               // edges per block in hist/bucket passes

typedef __attribute__((ext_vector_type(4))) float  f32x4;
typedef __attribute__((ext_vector_type(8))) short  bf16x8;

// bf16 helpers
__device__ __forceinline__ unsigned int pk_bf2(float lo, float hi) {
    __hip_bfloat162 h = __float22bfloat162_rn(make_float2(lo, hi));
    unsigned int u;
    __builtin_memcpy(&u, &h, 4);
    return u;
}
__device__ __forceinline__ float bf_lo(unsigned int v) { return __uint_as_float(v << 16); }
__device__ __forceinline__ float bf_hi(unsigned int v) { return __uint_as_float(v & 0xFFFF0000u); }

// ---------------------------------------------------------------------------
// Zero ints (grid-stride)
// ---------------------------------------------------------------------------
__global__ void zero_i_kernel(int* __restrict__ p, int n) {
    int i = blockIdx.x * blockDim.x + threadIdx.x;
    int s = gridDim.x * blockDim.x;
    for (; i < n; i += s) p[i] = 0;
}

// ---------------------------------------------------------------------------
// One-time: pack W (128x64 f32) into MFMA B-fragment order, bf16.
// wtab[(f*64+lane)*4 + e]; f = ct*4+kt; col = ct*16+(lane&15),
// k = kt*32+(lane>>4)*8 + 2e(+1).  16 KB total -> L1-resident in linear.
// ---------------------------------------------------------------------------
__global__ __launch_bounds__(256) void wfrag_kernel(
        const float* __restrict__ W, unsigned int* __restrict__ wtab) {
    const int t = threadIdx.x;
#pragma unroll
    for (int ii = 0; ii < 4; ++ii) {
        int fl   = ii * 256 + t;          // 0..1023 = f*64+lane
        int f    = fl >> 6;
        int lane = fl & 63;
        int ct = f >> 2, kt = f & 3;
        int n  = ct * 16 + (lane & 15);
        int kb = kt * 32 + (lane >> 4) * 8;
        unsigned int q[4];
#pragma unroll
        for (int e = 0; e < 4; ++e)
            q[e] = pk_bf2(W[(kb + 2 * e) * OUT_DIM + n],
                          W[(kb + 2 * e + 1) * OUT_DIM + n]);
        *reinterpret_cast<uint4*>(&wtab[fl * 4]) = *reinterpret_cast<uint4*>(q);
    }
}

// ---------------------------------------------------------------------------
// Bucket-level histogram (LDS-aggregated; no per-node atomics)
// ---------------------------------------------------------------------------
__global__ __launch_bounds__(256) void hist_kernel(
        const int* __restrict__ col, int* __restrict__ bhist, int E, int nbuck) {
    __shared__ int h[NBUCK_MAX];
    for (int i = threadIdx.x; i < nbuck; i += 256) h[i] = 0;
    __syncthreads();

    const int base = blockIdx.x * EPB;
    const int end  = min(base + EPB, E);
    for (int e = base + threadIdx.x; e < end; e += 256)
        atomicAdd(&h[col[e] >> BSHIFT], 1);
    __syncthreads();

    for (int i = threadIdx.x; i < nbuck; i += 256) {
        int v = h[i];
        if (v) atomicAdd(&bhist[i], v);
    }
}

// ---------------------------------------------------------------------------
// Exclusive scan of bhist -> bstart[0..nbuck]  (single block, 8 elems/thread)
// ---------------------------------------------------------------------------
__global__ __launch_bounds__(256) void scanb_kernel(
        const int* __restrict__ bhist, int* __restrict__ bstart, int nbuck) {
    __shared__ int ssum[256];
    const int t = threadIdx.x;
    int v[8];
    int run = 0;
#pragma unroll
    for (int j = 0; j < 8; ++j) {
        int idx = t * 8 + j;
        int x = (idx < nbuck) ? bhist[idx] : 0;
        v[j] = run;
        run += x;
    }
    ssum[t] = run;
    __syncthreads();
    for (int off = 1; off < 256; off <<= 1) {
        int tmp = (t >= off) ? ssum[t - off] : 0;
        __syncthreads();
        ssum[t] += tmp;
        __syncthreads();
    }
    int offset = (t > 0) ? ssum[t - 1] : 0;
#pragma unroll
    for (int j = 0; j < 8; ++j) {
        int idx = t * 8 + j;
        if (idx < nbuck) bstart[idx] = offset + v[j];
    }
    if (t == 255) bstart[nbuck] = ssum[255];   // total = E
}

// ---------------------------------------------------------------------------
// Scatter edges into bucket-major tmp, packed (r<<6 | c&63).
// ---------------------------------------------------------------------------
__global__ __launch_bounds__(256) void bucket_kernel(
        const int* __restrict__ eidx, const int* __restrict__ bstart,
        int* __restrict__ bcursor, int* __restrict__ tmp, int E, int nbuck) {
    __shared__ int hcnt[NBUCK_MAX];
    __shared__ int hbase[NBUCK_MAX];
    for (int i = threadIdx.x; i < nbuck; i += 256) hcnt[i] = 0;
    __syncthreads();

    const int base = blockIdx.x * EPB;
    const int end  = min(base + EPB, E);

    for (int e = base + threadIdx.x; e < end; e += 256)
        atomicAdd(&hcnt[eidx[E + e] >> BSHIFT], 1);
    __syncthreads();

    for (int i = threadIdx.x; i < nbuck; i += 256) {
        int n = hcnt[i];
        hbase[i] = n ? (bstart[i] + atomicAdd(&bcursor[i], n)) : 0;
        hcnt[i] = 0;           // reuse as local cursor
    }
    __syncthreads();

    for (int e = base + threadIdx.x; e < end; e += 256) {
        int r = eidx[e];
        int c = eidx[E + e];
        int bb = c >> BSHIFT;
        int ofs = atomicAdd(&hcnt[bb], 1);
        tmp[hbase[bb] + ofs] = (r << BSHIFT) | (c & (BSZ - 1));
    }
}

// ---------------------------------------------------------------------------
// Per-bucket: degree count -> rowptr + dis, then exact CSR placement.
// ---------------------------------------------------------------------------
__global__ __launch_bounds__(256) void sortloc_kernel(
        const int* __restrict__ tmp, const int* __restrict__ bstart,
        int* __restrict__ src, int* __restrict__ rowptr, float* __restrict__ dis,
        int N) {
    __shared__ int cnt[BSZ];
    __shared__ int pref[BSZ];
    __shared__ int scur[BSZ];

    const int bucket = blockIdx.x;
    const int sbeg = bstart[bucket];
    const int send = bstart[bucket + 1];
    const int tid = threadIdx.x;

    if (tid < BSZ) { cnt[tid] = 0; scur[tid] = 0; }
    __syncthreads();

    for (int i = sbeg + tid; i < send; i += 256)
        atomicAdd(&cnt[tmp[i] & (BSZ - 1)], 1);
    __syncthreads();

    if (tid == 0) {
        int run = 0;
#pragma unroll
        for (int j = 0; j < BSZ; ++j) { pref[j] = run; run += cnt[j]; }
    }
    __syncthreads();

    if (tid < BSZ) {
        int node = (bucket << BSHIFT) + tid;
        if (node < N) {
            rowptr[node] = sbeg + pref[tid];
            float d = (float)cnt[tid];
            dis[node] = (d > 0.f) ? rsqrtf(d) : 0.f;
        }
    }
    __syncthreads();

    for (int i = sbeg + tid; i < send; i += 256) {
        int p = tmp[i];
        int c = p & (BSZ - 1);
        int pos = sbeg + pref[c] + atomicAdd(&scur[c], 1);
        src[pos] = p >> BSHIFT;
    }
}

// ---------------------------------------------------------------------------
// MFMA linear: hsb = bf16( (x @ W) * dis[row] ), packed 2 cols/uint.
// B-frags read directly from the precomputed global frag table (16 KB,
// L1-resident; coalesced uint4 loads). No LDS, no sync.
// One 16-row tile per wave; 16 x mfma_f32_16x16x32_bf16 per tile.
// ---------------------------------------------------------------------------
__global__ __launch_bounds__(256) void linear_mfma_kernel(
        const float* __restrict__ x, const unsigned int* __restrict__ wtab,
        const float* __restrict__ dis, unsigned int* __restrict__ hsb, int nrows) {
    const int tid   = threadIdx.x;
    const int lane6 = tid & 63;
    const int wv    = tid >> 6;

    const int tile    = blockIdx.x * 4 + wv;
    const int rowbase = tile * 16;
    if (rowbase >= nrows) return;

    // B frags: global (L1-hot) -> VGPR, coalesced
    bf16x8 b[16];
#pragma unroll
    for (int f = 0; f < 16; ++f)
        b[f] = *reinterpret_cast<const bf16x8*>(&wtab[(f * 64 + lane6) * 4]);

    // A frags: global -> cvt bf16
    const int arow  = rowbase + (lane6 & 15);
    const int kbase = (lane6 >> 4) * 8;
    bf16x8 a[4];
#pragma unroll
    for (int kt = 0; kt < 4; ++kt) {
        const float4* p = reinterpret_cast<const float4*>(
            &x[(size_t)arow * IN_DIM + kt * 32 + kbase]);
        float4 f0 = p[0], f1 = p[1];
        unsigned int q[4] = { pk_bf2(f0.x, f0.y), pk_bf2(f0.z, f0.w),
                              pk_bf2(f1.x, f1.y), pk_bf2(f1.z, f1.w) };
        a[kt] = *reinterpret_cast<bf16x8*>(q);
    }

    f32x4 acc[4] = {{0,0,0,0},{0,0,0,0},{0,0,0,0},{0,0,0,0}};
#pragma unroll
    for (int ct = 0; ct < 4; ++ct)
#pragma unroll
        for (int kt = 0; kt < 4; ++kt)
            acc[ct] = __builtin_amdgcn_mfma_f32_16x16x32_bf16(
                a[kt], b[ct * 4 + kt], acc[ct], 0, 0, 0);

    // epilogue: * dis[row], pack col pairs, store
    const int rbase = rowbase + (lane6 >> 4) * 4;
    float dn[4];
#pragma unroll
    for (int r = 0; r < 4; ++r) dn[r] = dis[rbase + r];

#pragma unroll
    for (int ct = 0; ct < 4; ++ct) {
#pragma unroll
        for (int r = 0; r < 4; ++r) {
            float v = acc[ct][r] * dn[r];
            float vn = __shfl_down(v, 1, 64);
            if ((lane6 & 1) == 0) {
                int cpair = ct * 8 + ((lane6 & 15) >> 1);
                hsb[(size_t)(rbase + r) * (OUT_DIM / 2) + cpair] = pk_bf2(v, vn);
            }
        }
    }
}

// ---------------------------------------------------------------------------
// Aggregate + bias + PReLU: one wave per target node; each 32-lane half
// processes its own edge (32 lanes x bf16x2 = 128B row); halves combined
// via shfl_xor(32). 8 independent gathers in flight per half-wave.
// ---------------------------------------------------------------------------
__global__ __launch_bounds__(256) void agg_kernel(
        const int* __restrict__ rowptr, const int* __restrict__ src,
        const unsigned int* __restrict__ hsb, const float* __restrict__ dis,
        const float* __restrict__ b, const float* __restrict__ prelu_a,
        float* __restrict__ out, int N, int E) {
    const int lane = threadIdx.x & 63;
    const int half = lane >> 5;
    const int l32  = lane & 31;
    const int node = (blockIdx.x * blockDim.x + threadIdx.x) >> 6;
    if (node >= N) return;

    const int beg = rowptr[node];
    const int end = (node + 1 < N) ? rowptr[node + 1] : E;

    float a0 = 0.f, a1 = 0.f;
    int p = beg + half;
    // 8 independent gathers in flight per half-wave
    for (; p + 14 < end; p += 16) {
        int r0 = src[p],      r1 = src[p + 2],  r2 = src[p + 4],  r3 = src[p + 6];
        int r4 = src[p + 8],  r5 = src[p + 10], r6 = src[p + 12], r7 = src[p + 14];
        unsigned int v0 = hsb[(size_t)r0 * (OUT_DIM / 2) + l32];
        unsigned int v1 = hsb[(size_t)r1 * (OUT_DIM / 2) + l32];
        unsigned int v2 = hsb[(size_t)r2 * (OUT_DIM / 2) + l32];
        unsigned int v3 = hsb[(size_t)r3 * (OUT_DIM / 2) + l32];
        unsigned int v4 = hsb[(size_t)r4 * (OUT_DIM / 2) + l32];
        unsigned int v5 = hsb[(size_t)r5 * (OUT_DIM / 2) + l32];
        unsigned int v6 = hsb[(size_t)r6 * (OUT_DIM / 2) + l32];
        unsigned int v7 = hsb[(size_t)r7 * (OUT_DIM / 2) + l32];
        a0 += bf_lo(v0) + bf_lo(v1) + bf_lo(v2) + bf_lo(v3)
            + bf_lo(v4) + bf_lo(v5) + bf_lo(v6) + bf_lo(v7);
        a1 += bf_hi(v0) + bf_hi(v1) + bf_hi(v2) + bf_hi(v3)
            + bf_hi(v4) + bf_hi(v5) + bf_hi(v6) + bf_hi(v7);
    }
    // 4-deep tail
    for (; p + 6 < end; p += 8) {
        int r0 = src[p], r1 = src[p + 2], r2 = src[p + 4], r3 = src[p + 6];
        unsigned int v0 = hsb[(size_t)r0 * (OUT_DIM / 2) + l32];
        unsigned int v1 = hsb[(size_t)r1 * (OUT_DIM / 2) + l32];
        unsigned int v2 = hsb[(size_t)r2 * (OUT_DIM / 2) + l32];
        unsigned int v3 = hsb[(size_t)r3 * (OUT_DIM / 2) + l32];
        a0 += bf_lo(v0) + bf_lo(v1) + bf_lo(v2) + bf_lo(v3);
        a1 += bf_hi(v0) + bf_hi(v1) + bf_hi(v2) + bf_hi(v3);
    }
    for (; p < end; p += 2) {
        unsigned int v = hsb[(size_t)src[p] * (OUT_DIM / 2) + l32];
        a0 += bf_lo(v);
        a1 += bf_hi(v);
    }

    a0 += __shfl_xor(a0, 32, 64);
    a1 += __shfl_xor(a1, 32, 64);

    if (half == 0) {
        const float dn = dis[node];
        const float pa = prelu_a[0];
        int c0 = l32 * 2;
        float o0 = a0 * dn + b[c0];
        float o1 = a1 * dn + b[c0 + 1];
        o0 = (o0 >= 0.f) ? o0 : pa * o0;
        o1 = (o1 >= 0.f) ? o1 : pa * o1;
        *reinterpret_cast<float2*>(&out[(size_t)node * OUT_DIM + c0]) = make_float2(o0, o1);
    }
}

extern "C" void kernel_launch(void* const* d_in, const int* in_sizes, int n_in,
                              void* d_out, int out_size, void* d_ws, size_t ws_size,
                              hipStream_t stream) {
    const float* x    = (const float*)d_in[0];
    const int*   eidx = (const int*)d_in[1];
    const float* W    = (const float*)d_in[2];
    const float* b    = (const float*)d_in[3];
    const float* pa   = (const float*)d_in[4];
    float* out = (float*)d_out;

    const int N = in_sizes[0] / IN_DIM;        // 100000
    const int E = in_sizes[1] / 2;             // 1600000
    const int nbuck = (N + BSZ - 1) >> BSHIFT; // 1563
    const int nchunk = (E + EPB - 1) / EPB;    // 391
    const int ntiles = (N + 15) / 16;          // 6250
    const int nblk_lin = (ntiles + 3) / 4;     // 1563

    // workspace layout (4-byte elements):
    unsigned int* hsb = (unsigned int*)d_ws;                  // N*32 (bf16x2)
    int*   bhist   = (int*)(hsb + (size_t)N * (OUT_DIM / 2)); // NBUCK_MAX
    int*   bcursor = bhist + NBUCK_MAX;                       // NBUCK_MAX
    int*   bstart  = bcursor + NBUCK_MAX;                     // NBUCK_MAX+1
    int*   rowptr  = bstart + NBUCK_MAX + 1;                  // N
    float* dis     = (float*)(rowptr + N);                    // N
    int*   tmp     = (int*)(dis + N);                         // E
    int*   src     = tmp + E;                                 // E
    unsigned int* wtab = (unsigned int*)(src + E);            // 16*64*4 = 4096

    // 1) zero bhist + bcursor; pack W frag table
    zero_i_kernel<<<16, 256, 0, stream>>>(bhist, 2 * NBUCK_MAX);
    wfrag_kernel<<<1, 256, 0, stream>>>(W, wtab);

    // 2) bucket histogram
    hist_kernel<<<nchunk, 256, 0, stream>>>(eidx + E, bhist, E, nbuck);

    // 3) scan bhist -> bstart (+ total)
    scanb_kernel<<<1, 256, 0, stream>>>(bhist, bstart, nbuck);

    // 4) bucket-major scatter
    bucket_kernel<<<nchunk, 256, 0, stream>>>(eidx, bstart, bcursor, tmp, E, nbuck);

    // 5) per-bucket placement; emits rowptr + dis
    sortloc_kernel<<<nbuck, 256, 0, stream>>>(tmp, bstart, src, rowptr, dis, N);

    // 6) hsb = bf16((x @ W) * dis[row])  [MFMA, no LDS]
    linear_mfma_kernel<<<nblk_lin, 256, 0, stream>>>(x, wtab, dis, hsb, N);

    // 7) aggregate + bias + PReLU
    agg_kernel<<<(N * 64 + 255) / 256, 256, 0, stream>>>(
        rowptr, src, hsb, dis, b, pa, out, N, E);
}